// Round 1
// baseline (7372.026 us; speedup 1.0000x reference)
//
#include <hip/hip_runtime.h>

// Problem: B=8, N=HW=4096, D=512 (in), I=256 (inter), DO=512 (out)
// ws layout (floats): phi [8*4096*256] @0, theta @8388608, out1 [8*4096*512] @16777216
// Total ws use: 128 MB.

#define NB 8
#define NN 4096
#define ND 512
#define NI 256

// ---------------- K1: phi/theta = feat_vec @ w^T (tiled, fused pair) -------
// grid 1024 = B(8) x ntile(64) x half(2). Block tile: [64 n x 256 i], K=512.
// thread: ig = t&7 (i-group), nb = (t>>3)&31; owns 2 n (nb, nb+32) x 32 i (float4 x8)
__global__ __launch_bounds__(256) void k1_gemm_pt(
    const float* __restrict__ feat, const float* __restrict__ phi_w,
    const float* __restrict__ theta_w, float* __restrict__ phi,
    float* __restrict__ theta) {
  int bid = blockIdx.x;
  int b = bid >> 7;
  int rem = bid & 127;
  int n0 = (rem >> 1) << 6;
  int half = rem & 1;
  const float* __restrict__ wsrc = half ? theta_w : phi_w;
  float* __restrict__ wdst = half ? theta : phi;
  int t = threadIdx.x;
  int ig = t & 7, nb = (t >> 3) & 31;

  __shared__ float as[16][64];     // [k][n]
  __shared__ float bsT[16][260];   // [k][i], padded row for banks/alignment

  float acc[2][8][4];
#pragma unroll
  for (int h = 0; h < 2; h++)
#pragma unroll
    for (int j = 0; j < 8; j++)
#pragma unroll
      for (int l = 0; l < 4; l++) acc[h][j][l] = 0.0f;

  for (int k0 = 0; k0 < 512; k0 += 16) {
    __syncthreads();
#pragma unroll
    for (int s = 0; s < 4; s++) {
      int idx = s * 256 + t;
      int row = idx >> 6, col = idx & 63;
      as[row][col] = feat[(size_t)(b * 512 + k0 + row) * 4096 + n0 + col];
    }
#pragma unroll
    for (int s = 0; s < 16; s++) {
      int idx = s * 256 + t;
      int ii = idx >> 4, kk = idx & 15;
      bsT[kk][ii] = wsrc[ii * 512 + k0 + kk];
    }
    __syncthreads();
#pragma unroll
    for (int kk = 0; kk < 16; kk++) {
      float a0 = as[kk][nb];
      float a1 = as[kk][nb + 32];
#pragma unroll
      for (int j = 0; j < 8; j++) {
        float4 bv = *(const float4*)&bsT[kk][(ig + 8 * j) * 4];
        acc[0][j][0] += a0 * bv.x; acc[0][j][1] += a0 * bv.y;
        acc[0][j][2] += a0 * bv.z; acc[0][j][3] += a0 * bv.w;
        acc[1][j][0] += a1 * bv.x; acc[1][j][1] += a1 * bv.y;
        acc[1][j][2] += a1 * bv.z; acc[1][j][3] += a1 * bv.w;
      }
    }
  }
#pragma unroll
  for (int h = 0; h < 2; h++) {
    size_t rowb = ((size_t)b * 4096 + n0 + nb + 32 * h) * 256;
#pragma unroll
    for (int j = 0; j < 8; j++) {
      float4 v = make_float4(acc[h][j][0], acc[h][j][1], acc[h][j][2], acc[h][j][3]);
      *(float4*)&wdst[rowb + (ig + 8 * j) * 4] = v;
    }
  }
}

// ---------------- K2: row-wise L2 normalize (phi & theta, contiguous) ------
// grid 65536 blocks (one 256-float row each), block 256
__global__ __launch_bounds__(256) void k2_norm(float* __restrict__ pt) {
  int r = blockIdx.x;
  int t = threadIdx.x;
  size_t base = (size_t)r * 256;
  float v = pt[base + t];
  float ss = v * v;
#pragma unroll
  for (int off = 32; off > 0; off >>= 1) ss += __shfl_down(ss, off);
  __shared__ float red[4];
  __shared__ float rinv;
  int lane = t & 63, w = t >> 6;
  if (lane == 0) red[w] = ss;
  __syncthreads();
  if (t == 0) rinv = rsqrtf(red[0] + red[1] + red[2] + red[3]);
  __syncthreads();
  pt[base + t] = v * rinv;
}

// ---------------- K3: flash attention (no-max softmax; cos in [-1,1]) ------
// grid 1024 = B(8) x qtile(128). Q-tile 32 rows, K-tile 16, V chunked 4x128.
// thread: nl = t&15 (rows nl, nl+16), mg = t>>4 (m = mg; c = ch*128+mg*8+0..7)
__global__ __launch_bounds__(256) void k3_attn(
    const float* __restrict__ phi, const float* __restrict__ theta,
    const float* __restrict__ feat, float* __restrict__ out1) {
  int bid = blockIdx.x;
  int b = bid >> 7;
  int n0 = (bid & 127) << 5;
  int t = threadIdx.x;
  int nl = t & 15, mg = t >> 4;

  __shared__ float qs[32][260];
  __shared__ float ks[16][260];
  __shared__ float vs[16][132];
  __shared__ float ps[32][17];
  __shared__ float dred[32][17];

#pragma unroll 4
  for (int s = 0; s < 32; s++)
    qs[s][t] = phi[((size_t)b * 4096 + n0 + s) * 256 + t];

  float acc[2][4][8];  // [row][chunk][c-local]
#pragma unroll
  for (int h = 0; h < 2; h++)
#pragma unroll
    for (int c = 0; c < 4; c++)
#pragma unroll
      for (int l = 0; l < 8; l++) acc[h][c][l] = 0.0f;
  float dsa = 0.0f, dsb = 0.0f;

  for (int tile = 0; tile < 256; tile++) {
    int m0 = tile << 4;
    __syncthreads();  // A: prior ks/ps uses complete
#pragma unroll
    for (int s = 0; s < 16; s++)
      ks[s][t] = theta[((size_t)b * 4096 + m0 + s) * 256 + t];
    __syncthreads();  // B: ks ready

    float s0 = 0.0f, s1 = 0.0f;
    const float* qr0 = &qs[nl][0];
    const float* qr1 = &qs[nl + 16][0];
    const float* kr = &ks[mg][0];
#pragma unroll 8
    for (int k = 0; k < 256; k += 4) {
      float4 q0 = *(const float4*)(qr0 + k);
      float4 q1 = *(const float4*)(qr1 + k);
      float4 kv = *(const float4*)(kr + k);
      s0 += q0.x * kv.x + q0.y * kv.y + q0.z * kv.z + q0.w * kv.w;
      s1 += q1.x * kv.x + q1.y * kv.y + q1.z * kv.z + q1.w * kv.w;
    }
    float p0 = __expf(s0), p1 = __expf(s1);
    dsa += p0; dsb += p1;
    ps[nl][mg] = p0;
    ps[nl + 16][mg] = p1;

#pragma unroll 1
    for (int ch = 0; ch < 4; ch++) {
      __syncthreads();  // C: ps ready / prior vs use done
#pragma unroll
      for (int s = 0; s < 8; s++) {
        int idx = s * 256 + t;
        int j = idx & 15, c = idx >> 4;  // c in 0..127
        vs[j][c] = feat[((size_t)b * 512 + ch * 128 + c) * 4096 + m0 + j];
      }
      __syncthreads();  // D: vs ready
#pragma unroll
      for (int j = 0; j < 16; j++) {
        float pa = ps[nl][j];
        float pb = ps[nl + 16][j];
        const float* vr = &vs[j][mg * 8];
        float4 v0 = *(const float4*)(vr);
        float4 v1 = *(const float4*)(vr + 4);
        acc[0][ch][0] += pa * v0.x; acc[0][ch][1] += pa * v0.y;
        acc[0][ch][2] += pa * v0.z; acc[0][ch][3] += pa * v0.w;
        acc[0][ch][4] += pa * v1.x; acc[0][ch][5] += pa * v1.y;
        acc[0][ch][6] += pa * v1.z; acc[0][ch][7] += pa * v1.w;
        acc[1][ch][0] += pb * v0.x; acc[1][ch][1] += pb * v0.y;
        acc[1][ch][2] += pb * v0.z; acc[1][ch][3] += pb * v0.w;
        acc[1][ch][4] += pb * v1.x; acc[1][ch][5] += pb * v1.y;
        acc[1][ch][6] += pb * v1.z; acc[1][ch][7] += pb * v1.w;
      }
    }
  }

  __syncthreads();
  dred[nl][mg] = dsa;
  dred[nl + 16][mg] = dsb;
  __syncthreads();
  if (t < 32) {
    float s = 0.0f;
#pragma unroll
    for (int m = 0; m < 16; m++) s += dred[t][m];
    dred[t][16] = 1.0f / s;
  }
  __syncthreads();
  float ra = dred[nl][16];
  float rb = dred[nl + 16][16];
#pragma unroll
  for (int h = 0; h < 2; h++) {
    float rs = h ? rb : ra;
    size_t rowb = ((size_t)b * 4096 + n0 + nl + 16 * h) * 512;
#pragma unroll
    for (int ch = 0; ch < 4; ch++) {
      float4 o0 = make_float4(acc[h][ch][0] * rs, acc[h][ch][1] * rs,
                              acc[h][ch][2] * rs, acc[h][ch][3] * rs);
      float4 o1 = make_float4(acc[h][ch][4] * rs, acc[h][ch][5] * rs,
                              acc[h][ch][6] * rs, acc[h][ch][7] * rs);
      *(float4*)&out1[rowb + ch * 128 + mg * 8] = o0;
      *(float4*)&out1[rowb + ch * 128 + mg * 8 + 4] = o1;
    }
  }
}

// ---------------- K4: out = relu((out1 @ weight)^T), stored [B,512,4096] ---
// grid 4096 = B(8) x ntile(64) x dtile(8). Block tile [64 n x 64 d], K=512.
// thread: nc = t&15 (n = nc+16a), dc = t>>4 (d = d0+dc*4+j)
__global__ __launch_bounds__(256) void k4_out(
    const float* __restrict__ out1, const float* __restrict__ weight,
    float* __restrict__ out) {
  int bid = blockIdx.x;
  int b = bid >> 9;
  int rem = bid & 511;
  int n0 = (rem >> 3) << 6;
  int d0 = (rem & 7) << 6;
  int t = threadIdx.x;
  int nc = t & 15, dc = t >> 4;

  __shared__ float as[64][33];
  __shared__ float bs[32][68];

  float acc[4][4];
#pragma unroll
  for (int h = 0; h < 4; h++)
#pragma unroll
    for (int j = 0; j < 4; j++) acc[h][j] = 0.0f;

  for (int k0 = 0; k0 < 512; k0 += 32) {
    __syncthreads();
#pragma unroll
    for (int s = 0; s < 8; s++) {
      int idx = s * 256 + t;
      int row = idx >> 5, col = idx & 31;
      as[row][col] = out1[((size_t)b * 4096 + n0 + row) * 512 + k0 + col];
    }
#pragma unroll
    for (int s = 0; s < 8; s++) {
      int idx = s * 256 + t;
      int row = idx >> 6, col = idx & 63;
      bs[row][col] = weight[(size_t)(k0 + row) * 512 + d0 + col];
    }
    __syncthreads();
#pragma unroll
    for (int kk = 0; kk < 32; kk++) {
      float4 bv = *(const float4*)&bs[kk][dc * 4];
#pragma unroll
      for (int h = 0; h < 4; h++) {
        float a = as[nc + 16 * h][kk];
        acc[h][0] += a * bv.x; acc[h][1] += a * bv.y;
        acc[h][2] += a * bv.z; acc[h][3] += a * bv.w;
      }
    }
  }
#pragma unroll
  for (int h = 0; h < 4; h++) {
    int n = n0 + nc + 16 * h;
#pragma unroll
    for (int j = 0; j < 4; j++) {
      out[((size_t)b * 512 + d0 + dc * 4 + j) * 4096 + n] = fmaxf(acc[h][j], 0.0f);
    }
  }
}

extern "C" void kernel_launch(void* const* d_in, const int* in_sizes, int n_in,
                              void* d_out, int out_size, void* d_ws, size_t ws_size,
                              hipStream_t stream) {
  const float* feat    = (const float*)d_in[0];  // [8,512,64,64]
  const float* phi_w   = (const float*)d_in[1];  // [256,512]
  const float* theta_w = (const float*)d_in[2];  // [256,512]
  const float* weight  = (const float*)d_in[3];  // [512,512]
  float* out = (float*)d_out;                    // [8,512,64,64]
  float* ws = (float*)d_ws;
  float* phi   = ws;             // 8*4096*256
  float* theta = ws + 8388608;   // 8*4096*256
  float* out1  = ws + 16777216;  // 8*4096*512

  k1_gemm_pt<<<dim3(1024), dim3(256), 0, stream>>>(feat, phi_w, theta_w, phi, theta);
  k2_norm<<<dim3(65536), dim3(256), 0, stream>>>(ws);  // phi & theta rows contiguous
  k3_attn<<<dim3(1024), dim3(256), 0, stream>>>(phi, theta, feat, out1);
  k4_out<<<dim3(4096), dim3(256), 0, stream>>>(out1, weight, out);
}

// Round 2
// 1735.995 us; speedup vs baseline: 4.2466x; 4.2466x over previous
//
#include <hip/hip_runtime.h>

// B=8, N=HW=4096, D=512, I=256, DO=512
// ws layout (bytes):
//   [0,   64M): phi_f32 [8M floats] @0, theta_f32 @8388608 floats  (dead after k2)
//   [0, 33.5M): feat_bf (ushort), written by k0 AFTER k2 (overwrites phi/theta_f32)
//   [64M, 80M): phi_n bf16   (ushort offset 33554432)
//   [80M, 96M): theta_n bf16 (ushort offset 41943040)
//   [96M,128M): out1 bf16 [8,4096,512] (ushort offset 50331648)
// Total 128 MB (round-0 proved >=134 MB available).

typedef short s8v __attribute__((ext_vector_type(8)));
typedef float f4v __attribute__((ext_vector_type(4)));

__device__ inline ushort f2bf(float x) {
  union { float f; unsigned u; } v; v.f = x;
  unsigned u = v.u + 0x7fff + ((v.u >> 16) & 1);  // RNE
  return (ushort)(u >> 16);
}
__device__ inline float bf2f(ushort x) {
  union { unsigned u; float f; } v; v.u = ((unsigned)x) << 16; return v.f;
}

// ---------------- K1: phi/theta = feat_vec @ w^T (fp32, unchanged) --------
__global__ __launch_bounds__(256) void k1_gemm_pt(
    const float* __restrict__ feat, const float* __restrict__ phi_w,
    const float* __restrict__ theta_w, float* __restrict__ phi,
    float* __restrict__ theta) {
  int bid = blockIdx.x;
  int b = bid >> 7;
  int rem = bid & 127;
  int n0 = (rem >> 1) << 6;
  int half = rem & 1;
  const float* __restrict__ wsrc = half ? theta_w : phi_w;
  float* __restrict__ wdst = half ? theta : phi;
  int t = threadIdx.x;
  int ig = t & 7, nb = (t >> 3) & 31;

  __shared__ float as[16][64];
  __shared__ float bsT[16][260];

  float acc[2][8][4];
#pragma unroll
  for (int h = 0; h < 2; h++)
#pragma unroll
    for (int j = 0; j < 8; j++)
#pragma unroll
      for (int l = 0; l < 4; l++) acc[h][j][l] = 0.0f;

  for (int k0 = 0; k0 < 512; k0 += 16) {
    __syncthreads();
#pragma unroll
    for (int s = 0; s < 4; s++) {
      int idx = s * 256 + t;
      int row = idx >> 6, col = idx & 63;
      as[row][col] = feat[(size_t)(b * 512 + k0 + row) * 4096 + n0 + col];
    }
#pragma unroll
    for (int s = 0; s < 16; s++) {
      int idx = s * 256 + t;
      int ii = idx >> 4, kk = idx & 15;
      bsT[kk][ii] = wsrc[ii * 512 + k0 + kk];
    }
    __syncthreads();
#pragma unroll
    for (int kk = 0; kk < 16; kk++) {
      float a0 = as[kk][nb];
      float a1 = as[kk][nb + 32];
#pragma unroll
      for (int j = 0; j < 8; j++) {
        float4 bv = *(const float4*)&bsT[kk][(ig + 8 * j) * 4];
        acc[0][j][0] += a0 * bv.x; acc[0][j][1] += a0 * bv.y;
        acc[0][j][2] += a0 * bv.z; acc[0][j][3] += a0 * bv.w;
        acc[1][j][0] += a1 * bv.x; acc[1][j][1] += a1 * bv.y;
        acc[1][j][2] += a1 * bv.z; acc[1][j][3] += a1 * bv.w;
      }
    }
  }
#pragma unroll
  for (int h = 0; h < 2; h++) {
    size_t rowb = ((size_t)b * 4096 + n0 + nb + 32 * h) * 256;
#pragma unroll
    for (int j = 0; j < 8; j++) {
      float4 v = make_float4(acc[h][j][0], acc[h][j][1], acc[h][j][2], acc[h][j][3]);
      *(float4*)&wdst[rowb + (ig + 8 * j) * 4] = v;
    }
  }
}

// ---------------- K2: row L2-normalize fp32 -> bf16 ------------------------
__global__ __launch_bounds__(256) void k2_norm(const float* __restrict__ pt,
                                               ushort* __restrict__ ptn) {
  int r = blockIdx.x;
  int t = threadIdx.x;
  size_t base = (size_t)r * 256;
  float v = pt[base + t];
  float ss = v * v;
#pragma unroll
  for (int off = 32; off > 0; off >>= 1) ss += __shfl_down(ss, off);
  __shared__ float red[4];
  __shared__ float rinv;
  int lane = t & 63, w = t >> 6;
  if (lane == 0) red[w] = ss;
  __syncthreads();
  if (t == 0) rinv = rsqrtf(red[0] + red[1] + red[2] + red[3]);
  __syncthreads();
  ptn[base + t] = f2bf(v * rinv);
}

// ---------------- K0: feat fp32 -> bf16 (same [b][c][m] layout) ------------
__global__ __launch_bounds__(256) void k0_cast(const float* __restrict__ feat,
                                               ushort* __restrict__ feat_bf) {
  int idx = (blockIdx.x * 256 + threadIdx.x) * 4;
  float4 v = *(const float4*)&feat[idx];
  ushort4 u;
  u.x = f2bf(v.x); u.y = f2bf(v.y); u.z = f2bf(v.z); u.w = f2bf(v.w);
  *(ushort4*)&feat_bf[idx] = u;
}

// ---------------- K3: MFMA bf16 flash attention ----------------------------
// grid 512 = b(8, LSB for XCD affinity) x qtile(64). Q-tile 64 rows.
// 512 threads = 8 waves: rg = w&3 (16 Q-rows), ch = w>>2 (256 c-half).
__global__ __launch_bounds__(512) void k3_attn(
    const ushort* __restrict__ phi_n, const ushort* __restrict__ theta_n,
    const ushort* __restrict__ feat_bf, ushort* __restrict__ out1) {
  int bid = blockIdx.x;
  int b = bid & 7;
  int n0 = (bid >> 3) << 6;
  int t = threadIdx.x;
  int lane = t & 63;
  int w = t >> 6;
  int rg = w & 3, ch = w >> 2;
  int col = lane & 15, quad = lane >> 4;

  __shared__ ushort ks[64 * 264];   // K-tile [m][k], row stride 264
  __shared__ ushort ps[64 * 72];    // P [n][m], row stride 72
  __shared__ float dred[2][64];

  // Q A-frags straight from global: A[n=lane&15][k=quad*8+j]
  s8v qf[8];
  const ushort* qbase = phi_n + ((size_t)(b * 4096 + n0 + rg * 16 + col)) * 256;
#pragma unroll
  for (int f = 0; f < 8; f++)
    qf[f] = *(const s8v*)(qbase + f * 32 + quad * 8);

  f4v acc[16];
#pragma unroll
  for (int i = 0; i < 16; i++) acc[i] = (f4v){0.f, 0.f, 0.f, 0.f};
  float denp[4] = {0.f, 0.f, 0.f, 0.f};

  const ushort* thbase = theta_n + (size_t)b * 4096 * 256;
  const ushort* vbase = feat_bf + (size_t)b * 512 * 4096;

  for (int mt = 0; mt < 64; mt++) {
    int m0 = mt << 6;
    __syncthreads();  // prior ks/ps uses done
    {  // stage K-tile: 64 rows x 256 bf16, 8 threads/row
      int row = t >> 3, seg = t & 7;
      const ushort* src = thbase + (size_t)(m0 + row) * 256 + seg * 32;
      ushort* dst = ks + row * 264 + seg * 32;
#pragma unroll
      for (int u = 0; u < 4; u++)
        *(s8v*)(dst + u * 8) = *(const s8v*)(src + u * 8);
    }
    __syncthreads();  // ks ready

    // S = Q K^T: this wave: 16 n (rg) x 32 m (ch), two independent chains
    {
      f4v sv0 = (f4v){0.f, 0.f, 0.f, 0.f};
      f4v sv1 = (f4v){0.f, 0.f, 0.f, 0.f};
      const ushort* kb0 = ks + ((ch * 32) + col) * 264 + quad * 8;
      const ushort* kb1 = kb0 + 16 * 264;
#pragma unroll
      for (int kk = 0; kk < 8; kk++) {
        s8v b0 = *(const s8v*)(kb0 + kk * 32);
        s8v b1 = *(const s8v*)(kb1 + kk * 32);
        sv0 = __builtin_amdgcn_mfma_f32_16x16x32_bf16(qf[kk], b0, sv0, 0, 0, 0);
        sv1 = __builtin_amdgcn_mfma_f32_16x16x32_bf16(qf[kk], b1, sv1, 0, 0, 0);
      }
      // exp (cos in [-1,1]: no max needed), accumulate den, P -> LDS bf16
#pragma unroll
      for (int r = 0; r < 4; r++) {
        float p0 = __expf(sv0[r]);
        float p1 = __expf(sv1[r]);
        denp[r] += p0 + p1;
        int prow = rg * 16 + quad * 4 + r;
        ps[prow * 72 + ch * 32 + col] = f2bf(p0);
        ps[prow * 72 + ch * 32 + 16 + col] = f2bf(p1);
      }
    }
    __syncthreads();  // ps ready

    // PV: A = P rows rg*16.. from LDS; B = V frags straight from global
    s8v pf0, pf1;
    {
      const ushort* pb = ps + (rg * 16 + col) * 72 + quad * 8;
      pf0 = *(const s8v*)(pb);
      pf1 = *(const s8v*)(pb + 32);
    }
#pragma unroll
    for (int ct = 0; ct < 16; ct++) {
      const ushort* vp =
          vbase + (size_t)(ch * 256 + ct * 16 + col) * 4096 + m0 + quad * 8;
      s8v v0 = *(const s8v*)(vp);
      s8v v1 = *(const s8v*)(vp + 32);
      acc[ct] = __builtin_amdgcn_mfma_f32_16x16x32_bf16(pf0, v0, acc[ct], 0, 0, 0);
      acc[ct] = __builtin_amdgcn_mfma_f32_16x16x32_bf16(pf1, v1, acc[ct], 0, 0, 0);
    }
  }

  // den: reduce across the 16-lane col group (xor 1,2,4,8), then across ch
#pragma unroll
  for (int r = 0; r < 4; r++) {
    float d = denp[r];
    d += __shfl_xor(d, 1); d += __shfl_xor(d, 2);
    d += __shfl_xor(d, 4); d += __shfl_xor(d, 8);
    denp[r] = d;
  }
  if (col == 0) {
#pragma unroll
    for (int r = 0; r < 4; r++) dred[ch][rg * 16 + quad * 4 + r] = denp[r];
  }
  __syncthreads();
  float rden[4];
#pragma unroll
  for (int r = 0; r < 4; r++) {
    int n = rg * 16 + quad * 4 + r;
    rden[r] = 1.0f / (dred[0][n] + dred[1][n]);
  }
  // store out1 bf16 [b][n][c]
#pragma unroll
  for (int ct = 0; ct < 16; ct++) {
#pragma unroll
    for (int r = 0; r < 4; r++) {
      int n = n0 + rg * 16 + quad * 4 + r;
      out1[((size_t)b * 4096 + n) * 512 + ch * 256 + ct * 16 + col] =
          f2bf(acc[ct][r] * rden[r]);
    }
  }
}

// ---------------- K4: out = relu((out1 @ weight)^T) ------------------------
__global__ __launch_bounds__(256) void k4_out(
    const ushort* __restrict__ out1, const float* __restrict__ weight,
    float* __restrict__ out) {
  int bid = blockIdx.x;
  int b = bid >> 9;
  int rem = bid & 511;
  int n0 = (rem >> 3) << 6;
  int d0 = (rem & 7) << 6;
  int t = threadIdx.x;
  int nc = t & 15, dc = t >> 4;

  __shared__ float as[64][33];
  __shared__ float bs[32][68];

  float acc[4][4];
#pragma unroll
  for (int h = 0; h < 4; h++)
#pragma unroll
    for (int j = 0; j < 4; j++) acc[h][j] = 0.0f;

  for (int k0 = 0; k0 < 512; k0 += 32) {
    __syncthreads();
#pragma unroll
    for (int s = 0; s < 2; s++) {
      int chunk = s * 256 + t;      // 0..511, 4 bf16 each
      int linear = chunk * 4;
      int row = linear >> 5, c0 = linear & 31;
      const ushort* src = &out1[((size_t)b * 4096 + n0 + row) * 512 + k0 + c0];
      ushort4 u = *(const ushort4*)src;
      as[row][c0 + 0] = bf2f(u.x); as[row][c0 + 1] = bf2f(u.y);
      as[row][c0 + 2] = bf2f(u.z); as[row][c0 + 3] = bf2f(u.w);
    }
#pragma unroll
    for (int s = 0; s < 8; s++) {
      int idx = s * 256 + t;
      int row = idx >> 6, colw = idx & 63;
      bs[row][colw] = weight[(size_t)(k0 + row) * 512 + d0 + colw];
    }
    __syncthreads();
#pragma unroll
    for (int kk = 0; kk < 32; kk++) {
      float4 bv = *(const float4*)&bs[kk][dc * 4];
#pragma unroll
      for (int h = 0; h < 4; h++) {
        float a = as[nc + 16 * h][kk];
        acc[h][0] += a * bv.x; acc[h][1] += a * bv.y;
        acc[h][2] += a * bv.z; acc[h][3] += a * bv.w;
      }
    }
  }
#pragma unroll
  for (int h = 0; h < 4; h++) {
    int n = n0 + nc + 16 * h;
#pragma unroll
    for (int j = 0; j < 4; j++) {
      out[((size_t)b * 512 + d0 + dc * 4 + j) * 4096 + n] = fmaxf(acc[h][j], 0.0f);
    }
  }
}

extern "C" void kernel_launch(void* const* d_in, const int* in_sizes, int n_in,
                              void* d_out, int out_size, void* d_ws, size_t ws_size,
                              hipStream_t stream) {
  const float* feat    = (const float*)d_in[0];
  const float* phi_w   = (const float*)d_in[1];
  const float* theta_w = (const float*)d_in[2];
  const float* weight  = (const float*)d_in[3];
  float* out = (float*)d_out;
  float* ws = (float*)d_ws;

  float* phi_f   = ws;
  float* theta_f = ws + 8388608;
  ushort* wsu    = (ushort*)d_ws;
  ushort* feat_bf = wsu;                  // overwrites phi/theta_f after k2
  ushort* phi_n   = wsu + 33554432;
  ushort* theta_n = wsu + 41943040;
  ushort* out1    = wsu + 50331648;

  k1_gemm_pt<<<dim3(1024), dim3(256), 0, stream>>>(feat, phi_w, theta_w, phi_f, theta_f);
  k2_norm<<<dim3(65536), dim3(256), 0, stream>>>(phi_f, phi_n);  // phi+theta contiguous
  k0_cast<<<dim3(16384), dim3(256), 0, stream>>>(feat, feat_bf);
  k3_attn<<<dim3(512), dim3(512), 0, stream>>>(phi_n, theta_n, feat_bf, out1);
  k4_out<<<dim3(4096), dim3(256), 0, stream>>>(out1, weight, out);
}

// Round 3
// 605.554 us; speedup vs baseline: 12.1740x; 2.8668x over previous
//
#include <hip/hip_runtime.h>

// B=8, N=HW=4096, D=512, I=256, DO=512
// ws (ushort offsets):
//   featT  @0        [b][n=4096][c=512] bf16 (k0a->k1); overlaid by out1 (k3->k4)
//   featV  @16777216 [b][mt=64][c=512][m=64] bf16 (k0a->k3)
//   phi_n  @33554432 [b][n][i=256] bf16 normalized (k1->k3)
//   theta_n@41943040 same (k1->k3)
//   wb_phi @50331648 [i=256][c=512] bf16 (k0b->k1)
//   wb_th  @50462720
//   weightT@50593792 [d=512][c=512] bf16 (k0c->k4)
// end 50855936 ushorts = 101.7 MB (<= proven 134 MB)

typedef short s8v __attribute__((ext_vector_type(8)));
typedef float f4v __attribute__((ext_vector_type(4)));

__device__ inline ushort f2bf(float x) {
  union { float f; unsigned u; } v; v.f = x;
  unsigned u = v.u + 0x7fff + ((v.u >> 16) & 1);
  return (ushort)(u >> 16);
}

// ---------- k0a: feat fp32 [b][c][m] -> featV blocked bf16 + featT bf16 ----
// grid 4096 = 8b x 8cb x 64mt, block 256
__global__ __launch_bounds__(256) void k0a(const float* __restrict__ feat,
                                           ushort* __restrict__ featT,
                                           ushort* __restrict__ featV) {
  int bid = blockIdx.x;
  int b = bid >> 9, cb = (bid >> 6) & 7, mt = bid & 63;
  int t = threadIdx.x;
  __shared__ ushort tile[64][72];

#pragma unroll
  for (int p = 0; p < 4; p++) {
    int ci = p * 16 + (t >> 4);
    int mi = (t & 15) * 4;
    float4 v = *(const float4*)&feat[((size_t)(b * 512 + cb * 64 + ci)) * 4096 + mt * 64 + mi];
    ushort4 u; u.x = f2bf(v.x); u.y = f2bf(v.y); u.z = f2bf(v.z); u.w = f2bf(v.w);
    *(ushort4*)&featV[((size_t)(b * 64 + mt) * 512 + cb * 64 + ci) * 64 + mi] = u;
    tile[ci][mi] = u.x; tile[ci][mi + 1] = u.y; tile[ci][mi + 2] = u.z; tile[ci][mi + 3] = u.w;
  }
  __syncthreads();
  int m = t >> 2, cs = (t & 3) * 16;
  ushort tmp[16];
#pragma unroll
  for (int j = 0; j < 16; j++) tmp[j] = tile[cs + j][m];
  ushort* dst = &featT[((size_t)(b * 4096 + mt * 64 + m)) * 512 + cb * 64 + cs];
  *(s8v*)dst = *(s8v*)&tmp[0];
  *(s8v*)(dst + 8) = *(s8v*)&tmp[8];
}

// ---------- k0b: cast phi_w / theta_w -> bf16 ------------------------------
__global__ __launch_bounds__(256) void k0b(const float* __restrict__ pw,
                                           const float* __restrict__ tw,
                                           ushort* __restrict__ wbp,
                                           ushort* __restrict__ wbt) {
  int bid = blockIdx.x;
  const float* src = (bid < 128) ? pw : tw;
  ushort* dst = (bid < 128) ? wbp : wbt;
  int idx = ((bid & 127) * 256 + threadIdx.x) * 4;
  float4 v = *(const float4*)&src[idx];
  ushort4 u; u.x = f2bf(v.x); u.y = f2bf(v.y); u.z = f2bf(v.z); u.w = f2bf(v.w);
  *(ushort4*)&dst[idx] = u;
}

// ---------- k0c: weight fp32 [c][d] -> weightT bf16 [d][c] -----------------
// grid 64 = 8cb x 8db
__global__ __launch_bounds__(256) void k0c(const float* __restrict__ w,
                                           ushort* __restrict__ wT) {
  int bid = blockIdx.x;
  int cb = bid >> 3, db = bid & 7;
  int t = threadIdx.x;
  __shared__ ushort tile[64][72];
#pragma unroll
  for (int p = 0; p < 4; p++) {
    int ci = p * 16 + (t >> 4);
    int di = (t & 15) * 4;
    float4 v = *(const float4*)&w[(size_t)(cb * 64 + ci) * 512 + db * 64 + di];
    tile[ci][di] = f2bf(v.x); tile[ci][di + 1] = f2bf(v.y);
    tile[ci][di + 2] = f2bf(v.z); tile[ci][di + 3] = f2bf(v.w);
  }
  __syncthreads();
  int d = t >> 2, cs = (t & 3) * 16;
  ushort tmp[16];
#pragma unroll
  for (int j = 0; j < 16; j++) tmp[j] = tile[cs + j][d];
  ushort* dst = &wT[(size_t)(db * 64 + d) * 512 + cb * 64 + cs];
  *(s8v*)dst = *(s8v*)&tmp[0];
  *(s8v*)(dst + 8) = *(s8v*)&tmp[8];
}

// ---------- k1: phi/theta MFMA GEMM + fused L2-normalize -> bf16 -----------
// grid 512 = 8b x 32nt x 2half, block 512 (8 waves x 16 n-rows, all 256 i)
__global__ __launch_bounds__(512) void k1_gemm(
    const ushort* __restrict__ featT, const ushort* __restrict__ wbp,
    const ushort* __restrict__ wbt, ushort* __restrict__ phi_n,
    ushort* __restrict__ theta_n) {
  int bid = blockIdx.x;
  int b = bid & 7;
  int rest = bid >> 3;
  int half = rest & 1;
  int nt = rest >> 1;
  const ushort* wb = half ? wbt : wbp;
  ushort* dst = half ? theta_n : phi_n;
  int t = threadIdx.x;
  int lane = t & 63, w = t >> 6;
  int col = lane & 15, quad = lane >> 4;
  int n0 = nt * 128;

  const ushort* abase =
      featT + ((size_t)(b * 4096 + n0 + w * 16 + col)) * 512 + quad * 8;

  f4v acc[16];
#pragma unroll
  for (int i = 0; i < 16; i++) acc[i] = (f4v){0.f, 0.f, 0.f, 0.f};

#pragma unroll 2
  for (int kc = 0; kc < 16; kc++) {
    s8v a = *(const s8v*)(abase + kc * 32);
#pragma unroll
    for (int it = 0; it < 16; it++) {
      s8v bf = *(const s8v*)(wb + (size_t)(it * 16 + col) * 512 + kc * 32 + quad * 8);
      acc[it] = __builtin_amdgcn_mfma_f32_16x16x32_bf16(a, bf, acc[it], 0, 0, 0);
    }
  }
  // fused normalize: lane holds rows n = w*16 + quad*4 + reg, cols i = it*16+col
  float rinv[4];
#pragma unroll
  for (int reg = 0; reg < 4; reg++) {
    float ss = 0.f;
#pragma unroll
    for (int it = 0; it < 16; it++) ss += acc[it][reg] * acc[it][reg];
    ss += __shfl_xor(ss, 1); ss += __shfl_xor(ss, 2);
    ss += __shfl_xor(ss, 4); ss += __shfl_xor(ss, 8);
    rinv[reg] = rsqrtf(ss);
  }
#pragma unroll
  for (int it = 0; it < 16; it++) {
#pragma unroll
    for (int reg = 0; reg < 4; reg++) {
      dst[((size_t)(b * 4096 + n0 + w * 16 + quad * 4 + reg)) * 256 + it * 16 + col] =
          f2bf(acc[it][reg] * rinv[reg]);
    }
  }
}

// ---------- k3: MFMA flash attention, swizzled LDS, K-dbuf, blocked V ------
// grid 512 = 8b(LSB) x 64qt, block 512 = 8 waves.
// QK role: rg=w&3 (16 q-rows), mh=w>>2 (32-m half). PV role: wave owns c [w*64,+64)
__global__ __launch_bounds__(512) void k3_attn(
    const ushort* __restrict__ phi_n, const ushort* __restrict__ theta_n,
    const ushort* __restrict__ featV, ushort* __restrict__ out1) {
  int bid = blockIdx.x;
  int b = bid & 7;
  int n0 = (bid >> 3) << 6;
  int t = threadIdx.x;
  int lane = t & 63, w = t >> 6;
  int col = lane & 15, quad = lane >> 4;
  int rg = w & 3, mh = w >> 2;
  int l32 = lane & 31, h32 = lane >> 5;

  __shared__ __align__(16) ushort ks[2 * 16384];  // [buf][row*256 + (chunk^ (row&7))*8]
  __shared__ __align__(16) ushort ps[4096];       // [n*64 + (chunk^(n&7))*8]
  __shared__ float dred[128];

  // Q A-frags (persistent): A[n=rg*16+col][k=f*32+quad*8+j]
  s8v qf[8];
  {
    const ushort* qb = phi_n + ((size_t)(b * 4096 + n0 + rg * 16 + col)) * 256 + quad * 8;
#pragma unroll
    for (int f = 0; f < 8; f++) qf[f] = *(const s8v*)(qb + f * 32);
  }

  const ushort* thb = theta_n + (size_t)b * 4096 * 256;
  const ushort* vbb = featV + (size_t)b * 64 * 512 * 64 + (size_t)(w * 64) * 64;

  f4v acc[16];
#pragma unroll
  for (int i = 0; i < 16; i++) acc[i] = (f4v){0.f, 0.f, 0.f, 0.f};
  float denp[4] = {0.f, 0.f, 0.f, 0.f};

  // stage tile 0 into buf 0
#pragma unroll
  for (int u = 0; u < 4; u++) {
    int row = w * 8 + u * 2 + h32;
    s8v val = *(const s8v*)(thb + (size_t)row * 256 + l32 * 8);
    *(s8v*)(ks + row * 256 + ((l32 ^ (row & 7)) * 8)) = val;
  }
  __syncthreads();

#pragma unroll 1
  for (int mt = 0; mt < 64; mt++) {
    const ushort* kc_ = ks + (mt & 1) * 16384;
    ushort* kn_ = ks + ((mt & 1) ^ 1) * 16384;

    // prefetch next K tile into regs
    s8v kreg[4];
    if (mt < 63) {
      int m1 = (mt + 1) << 6;
#pragma unroll
      for (int u = 0; u < 4; u++) {
        int row = w * 8 + u * 2 + h32;
        kreg[u] = *(const s8v*)(thb + (size_t)(m1 + row) * 256 + l32 * 8);
      }
    }
    // V B-frags for this tile (blocked layout, 2KB window per ct-pair)
    s8v v0[4], v1[4];
    {
      const ushort* vb = vbb + (size_t)mt * 32768;
#pragma unroll
      for (int ct = 0; ct < 4; ct++) {
        const ushort* p = vb + (ct * 16 + col) * 64 + quad * 8;
        v0[ct] = *(const s8v*)p;
        v1[ct] = *(const s8v*)(p + 32);
      }
    }

    // QK: S[16 rg-rows][32 mh-cols], two 16-col subtiles
    f4v sv0 = (f4v){0.f, 0.f, 0.f, 0.f};
    f4v sv1 = (f4v){0.f, 0.f, 0.f, 0.f};
    {
      int rm = mh * 32 + col;  // rm&7 == col&7
      const ushort* kb = kc_ + rm * 256;
#pragma unroll
      for (int kk = 0; kk < 8; kk++) {
        int pos = ((kk * 4 + quad) ^ (col & 7)) * 8;
        s8v b0 = *(const s8v*)(kb + pos);
        s8v b1 = *(const s8v*)(kb + 16 * 256 + pos);
        sv0 = __builtin_amdgcn_mfma_f32_16x16x32_bf16(qf[kk], b0, sv0, 0, 0, 0);
        sv1 = __builtin_amdgcn_mfma_f32_16x16x32_bf16(qf[kk], b1, sv1, 0, 0, 0);
      }
    }
    float p0[4], p1[4];
#pragma unroll
    for (int r = 0; r < 4; r++) {
      p0[r] = __expf(sv0[r]);
      p1[r] = __expf(sv1[r]);
      denp[r] += p0[r] + p1[r];
    }

    __syncthreads();  // b1: prior PV done reading ps

    // P -> LDS (swizzled), rows n = rg*16+quad*4+r, cols mh*32+col / +16
#pragma unroll
    for (int r = 0; r < 4; r++) {
      int n = rg * 16 + quad * 4 + r;
      int j0 = mh * 4 + (col >> 3);
      ps[n * 64 + ((j0 ^ (n & 7)) * 8) + (col & 7)] = f2bf(p0[r]);
      ps[n * 64 + (((j0 + 2) ^ (n & 7)) * 8) + (col & 7)] = f2bf(p1[r]);
    }
    // write next K tile to other buffer
    if (mt < 63) {
#pragma unroll
      for (int u = 0; u < 4; u++) {
        int row = w * 8 + u * 2 + h32;
        *(s8v*)(kn_ + row * 256 + ((l32 ^ (row & 7)) * 8)) = kreg[u];
      }
    }
    __syncthreads();  // b2: ps + ks[next] ready

    // PV: A = P (all 4 rowsets), B = v0/v1 (this wave's 64-c range)
#pragma unroll
    for (int rs = 0; rs < 4; rs++) {
      const ushort* pb = ps + (rs * 16 + col) * 64;
      s8v pf0 = *(const s8v*)(pb + ((quad ^ (col & 7)) * 8));
      s8v pf1 = *(const s8v*)(pb + (((quad + 4) ^ (col & 7)) * 8));
#pragma unroll
      for (int ct = 0; ct < 4; ct++) {
        acc[rs * 4 + ct] =
            __builtin_amdgcn_mfma_f32_16x16x32_bf16(pf0, v0[ct], acc[rs * 4 + ct], 0, 0, 0);
        acc[rs * 4 + ct] =
            __builtin_amdgcn_mfma_f32_16x16x32_bf16(pf1, v1[ct], acc[rs * 4 + ct], 0, 0, 0);
      }
    }
  }

  // denominator: reduce over col-group then across mh halves
#pragma unroll
  for (int r = 0; r < 4; r++) {
    float d = denp[r];
    d += __shfl_xor(d, 1); d += __shfl_xor(d, 2);
    d += __shfl_xor(d, 4); d += __shfl_xor(d, 8);
    denp[r] = d;
  }
  if (col == 0) {
#pragma unroll
    for (int r = 0; r < 4; r++) dred[mh * 64 + rg * 16 + quad * 4 + r] = denp[r];
  }
  __syncthreads();
  if (t < 64) dred[t] = 1.0f / (dred[t] + dred[64 + t]);
  __syncthreads();

  // store out1 bf16 [n][c]: D[n=rs*16+quad*4+reg][c=w*64+ct*16+col]
#pragma unroll
  for (int rs = 0; rs < 4; rs++) {
#pragma unroll
    for (int ct = 0; ct < 4; ct++) {
#pragma unroll
      for (int reg = 0; reg < 4; reg++) {
        int n = rs * 16 + quad * 4 + reg;
        out1[((size_t)(b * 4096 + n0 + n)) * 512 + w * 64 + ct * 16 + col] =
            f2bf(acc[rs * 4 + ct][reg] * dred[n]);
      }
    }
  }
}

// ---------- k4: out = relu(weightT_bf @ out1^T) stored [b][d][n] fp32 ------
// grid 512 = 8b x 4dt x 16nt, block 512 = 8 waves (dw=w&1 -> 64d, nw=w>>1 -> 64n)
__global__ __launch_bounds__(512) void k4_out(
    const ushort* __restrict__ out1, const ushort* __restrict__ wT,
    float* __restrict__ out) {
  int bid = blockIdx.x;
  int b = bid & 7;
  int rest = bid >> 3;
  int dt = rest & 3;
  int nt = rest >> 2;
  int t = threadIdx.x;
  int lane = t & 63, w = t >> 6;
  int col = lane & 15, quad = lane >> 4;
  int dw = w & 1, nw = w >> 1;
  int d0 = dt * 128 + dw * 64;
  int n0 = nt * 256 + nw * 64;

  f4v acc[16];
#pragma unroll
  for (int i = 0; i < 16; i++) acc[i] = (f4v){0.f, 0.f, 0.f, 0.f};

#pragma unroll 2
  for (int kc = 0; kc < 16; kc++) {
    s8v af[4], bf[4];
#pragma unroll
    for (int rs = 0; rs < 4; rs++)
      af[rs] = *(const s8v*)(wT + (size_t)(d0 + rs * 16 + col) * 512 + kc * 32 + quad * 8);
#pragma unroll
    for (int ct = 0; ct < 4; ct++)
      bf[ct] = *(const s8v*)(out1 + ((size_t)(b * 4096 + n0 + ct * 16 + col)) * 512 +
                             kc * 32 + quad * 8);
#pragma unroll
    for (int rs = 0; rs < 4; rs++)
#pragma unroll
      for (int ct = 0; ct < 4; ct++)
        acc[rs * 4 + ct] =
            __builtin_amdgcn_mfma_f32_16x16x32_bf16(af[rs], bf[ct], acc[rs * 4 + ct], 0, 0, 0);
  }
#pragma unroll
  for (int rs = 0; rs < 4; rs++) {
#pragma unroll
    for (int ct = 0; ct < 4; ct++) {
#pragma unroll
      for (int reg = 0; reg < 4; reg++) {
        int d = d0 + rs * 16 + quad * 4 + reg;
        int n = n0 + ct * 16 + col;
        out[((size_t)(b * 512 + d)) * 4096 + n] = fmaxf(acc[rs * 4 + ct][reg], 0.f);
      }
    }
  }
}

extern "C" void kernel_launch(void* const* d_in, const int* in_sizes, int n_in,
                              void* d_out, int out_size, void* d_ws, size_t ws_size,
                              hipStream_t stream) {
  const float* feat    = (const float*)d_in[0];
  const float* phi_w   = (const float*)d_in[1];
  const float* theta_w = (const float*)d_in[2];
  const float* weight  = (const float*)d_in[3];
  float* out = (float*)d_out;

  ushort* wsu = (ushort*)d_ws;
  ushort* featT   = wsu;                    // dead after k1 -> reused as out1
  ushort* featV   = wsu + 16777216;
  ushort* phi_n   = wsu + 33554432;
  ushort* theta_n = wsu + 41943040;
  ushort* wbp     = wsu + 50331648;
  ushort* wbt     = wsu + 50462720;
  ushort* weightT = wsu + 50593792;
  ushort* out1    = wsu;                    // overlays featT

  k0a<<<dim3(4096), dim3(256), 0, stream>>>(feat, featT, featV);
  k0b<<<dim3(256), dim3(256), 0, stream>>>(phi_w, theta_w, wbp, wbt);
  k0c<<<dim3(64), dim3(256), 0, stream>>>(weight, weightT);
  k1_gemm<<<dim3(512), dim3(512), 0, stream>>>(featT, wbp, wbt, phi_n, theta_n);
  k3_attn<<<dim3(512), dim3(512), 0, stream>>>(phi_n, theta_n, featV, out1);
  k4_out<<<dim3(512), dim3(512), 0, stream>>>(out1, weightT, out);
}